// Round 2
// baseline (252.073 us; speedup 1.0000x reference)
//
#include <hip/hip_runtime.h>

typedef unsigned int u32;
typedef unsigned short u16;
typedef unsigned long long u64;

typedef __attribute__((ext_vector_type(4))) float f32x4;
typedef __attribute__((ext_vector_type(8))) __bf16 bf16x8;
typedef __attribute__((ext_vector_type(8))) u16 u16x8;
typedef __attribute__((ext_vector_type(4))) u16 u16x4;

#define NB 256
#define ND 512
#define NC 100000
#define NC4 25000              // NC/4 float4s per row
#define CAP 524288             // u64 collect entries (4 MB)
#define THRC 0.08f             // static collect threshold << neg_th (~0.19)
#define EXP2K 92.33248261689366f   // 64*log2(e)

// ---- ws layout (bytes), within round-1 footprint (107,278,592 B) ----
#define OFF_EMBN  0            // u16 [256*512] = 262144
#define OFF_TGT   262144       // f32 [256]
#define OFF_SEXP  263168       // f32 [256]
#define OFF_AMAX  264192       // u32 [256]
#define OFF_SCAL  265216       // u32 {topk, bufcnt}
#define OFF_COS   662528       // f32 [256*100000] = 102400000
#define OFF_BUF   103084288    // u64 [CAP] = 4194304

__device__ __forceinline__ u32 ordkey(float f) {
  u32 u = __float_as_uint(f);
  return (u & 0x80000000u) ? ~u : (u | 0x80000000u);
}
__device__ __forceinline__ float inv_ordkey(u32 key) {
  u32 u = (key & 0x80000000u) ? (key & 0x7FFFFFFFu) : ~key;
  return __uint_as_float(u);
}
__device__ __forceinline__ u16 f2bf(float x) {  // RNE f32->bf16
  u32 u = __float_as_uint(x);
  return (u16)((u + 0x7FFFu + ((u >> 16) & 1u)) >> 16);
}

// ---------------- K0: normalize embedding rows -> bf16 ----------------
__global__ void k_prep(const float* __restrict__ emb, u16* __restrict__ embn) {
  __shared__ float s[128];
  const int r = blockIdx.x, t = threadIdx.x;
  float4 v = *(const float4*)(emb + r * ND + t * 4);
  s[t] = v.x * v.x + v.y * v.y + v.z * v.z + v.w * v.w;
  __syncthreads();
  for (int st = 64; st > 0; st >>= 1) { if (t < st) s[t] += s[t + st]; __syncthreads(); }
  const float rinv = 1.0f / sqrtf(s[0]);
  u16x4 o = { f2bf(v.x * rinv), f2bf(v.y * rinv), f2bf(v.z * rinv), f2bf(v.w * rinv) };
  *(u16x4*)(embn + r * ND + t * 4) = o;
}

// ---------------- K1: bf16 MFMA GEMM with fused column-norm -----------
// tile: M=256 (all rows) x N=128, K-steps of 64. 8 waves = 2(M) x 4(N).
// Column sum-of-squares accumulated during B staging (each block reads
// its columns' full K extent), LDS-tree reduced -> epilogue scaling.
__global__ __launch_bounds__(512) void k_gemm(const float* __restrict__ kern,
                                              const u16* __restrict__ embn,
                                              float* __restrict__ cosb) {
  __shared__ u16 At[256 * 72];       // [m][k] pad 72 (rows 144B)
  __shared__ u16 Bt[64 * 132];       // [k][n] pad 132
  __shared__ float colp[16][128];    // column ssq partials [bd][col]
  const int tid = threadIdx.x;
  const int lane = tid & 63;
  const int w = tid >> 6;
  const int mbase = (w >> 2) * 128, nbase = (w & 3) * 32;
  const int l15 = lane & 15, g = lane >> 4;
  const int cblk = blockIdx.x * 128;

  f32x4 acc[8][2];
  #pragma unroll
  for (int i = 0; i < 8; ++i)
    for (int j = 0; j < 2; ++j) acc[i][j] = (f32x4){0.f, 0.f, 0.f, 0.f};

  const int am = tid >> 1, ah = (tid & 1) * 32;   // A staging
  const int bc4 = (tid & 31) * 4, bd = tid >> 5;  // B staging
  float ss0 = 0.f, ss1 = 0.f, ss2 = 0.f, ss3 = 0.f;

  for (int ks = 0; ks < 8; ++ks) {
    const int k0 = ks * 64;
    // stage A [256][64] from embn (bf16, L2-hot)
    #pragma unroll
    for (int j = 0; j < 4; ++j) {
      u16x8 v = *(const u16x8*)(embn + am * ND + k0 + ah + j * 8);
      *(u16x8*)(At + am * 72 + ah + j * 8) = v;
    }
    // stage B [64][128] from kern fp32 -> bf16, accumulate ssq
    #pragma unroll
    for (int i = 0; i < 4; ++i) {
      const int d = bd + i * 16;
      const int gc = cblk + bc4;
      const float* src = kern + (size_t)(k0 + d) * NC + gc;
      float x0 = 0.f, x1 = 0.f, x2 = 0.f, x3 = 0.f;
      if (gc + 3 < NC) {
        float4 f = *(const float4*)src;
        x0 = f.x; x1 = f.y; x2 = f.z; x3 = f.w;
      } else {
        if (gc + 0 < NC) x0 = src[0];
        if (gc + 1 < NC) x1 = src[1];
        if (gc + 2 < NC) x2 = src[2];
        if (gc + 3 < NC) x3 = src[3];
      }
      ss0 += x0 * x0; ss1 += x1 * x1; ss2 += x2 * x2; ss3 += x3 * x3;
      u16x4 b4 = { f2bf(x0), f2bf(x1), f2bf(x2), f2bf(x3) };
      *(u16x4*)(Bt + d * 132 + bc4) = b4;
    }
    __syncthreads();
    #pragma unroll
    for (int kf = 0; kf < 2; ++kf) {
      bf16x8 bfr[2];
      #pragma unroll
      for (int nf = 0; nf < 2; ++nf) {
        const int n = nbase + nf * 16 + l15;
        u16x8 bu;
        #pragma unroll
        for (int i = 0; i < 8; ++i) bu[i] = Bt[(kf * 32 + g * 8 + i) * 132 + n];
        bfr[nf] = __builtin_bit_cast(bf16x8, bu);
      }
      #pragma unroll
      for (int mf = 0; mf < 8; ++mf) {
        const int m = mbase + mf * 16 + l15;
        bf16x8 av = *(const bf16x8*)(At + m * 72 + kf * 32 + g * 8);
        acc[mf][0] = __builtin_amdgcn_mfma_f32_16x16x32_bf16(av, bfr[0], acc[mf][0], 0, 0, 0);
        acc[mf][1] = __builtin_amdgcn_mfma_f32_16x16x32_bf16(av, bfr[1], acc[mf][1], 0, 0, 0);
      }
    }
    __syncthreads();
  }
  // reduce column ssq partials (deterministic tree over bd)
  colp[bd][bc4 + 0] = ss0; colp[bd][bc4 + 1] = ss1;
  colp[bd][bc4 + 2] = ss2; colp[bd][bc4 + 3] = ss3;
  __syncthreads();
  for (int st = 8; st > 0; st >>= 1) {
    if (bd < st) {
      colp[bd][bc4 + 0] += colp[bd + st][bc4 + 0];
      colp[bd][bc4 + 1] += colp[bd + st][bc4 + 1];
      colp[bd][bc4 + 2] += colp[bd + st][bc4 + 2];
      colp[bd][bc4 + 3] += colp[bd + st][bc4 + 3];
    }
    __syncthreads();
  }
  // epilogue: scale by 1/colnorm, clip, store. C/D: col=lane&15, row=(lane>>4)*4+reg
  #pragma unroll
  for (int nf = 0; nf < 2; ++nf) {
    const int nl = nbase + nf * 16 + l15;
    const int c = cblk + nl;
    if (c >= NC) continue;
    const float cinv = 1.0f / sqrtf(colp[0][nl]);
    #pragma unroll
    for (int mf = 0; mf < 8; ++mf) {
      const int mrow = mbase + mf * 16 + g * 4;
      #pragma unroll
      for (int r = 0; r < 4; ++r) {
        float v = acc[mf][nf][r] * cinv;
        v = fminf(fmaxf(v, -1.0f), 1.0f);
        cosb[(size_t)(mrow + r) * NC + c] = v;
      }
    }
  }
}

// ---------------- K2: single full pass over cos -----------------------
// per row: topk count, argmax, sum(exp2(K*v)), collect non-topk >= THRC
__global__ __launch_bounds__(1024) void k_scan(const float* __restrict__ cosb,
                                               const int* __restrict__ lab,
                                               float* __restrict__ tgtws,
                                               float* __restrict__ sexpws,
                                               u32* __restrict__ amaxws,
                                               u32* __restrict__ scal,
                                               u64* __restrict__ buf) {
  __shared__ u32 sc[1024];
  __shared__ float se[1024];
  __shared__ u64 sm[1024];
  __shared__ float stg;
  const int tid = threadIdx.x, r = blockIdx.x;
  const int lb = lab[r];
  const float* row = cosb + (size_t)r * NC;
  if (tid == 0) { float t = row[lb]; stg = t; tgtws[r] = t; }
  __syncthreads();
  const float tg = stg;
  u32 cnt = 0; float sexp = 0.f; u64 best = 0;
  for (int i = tid; i < NC4; i += 1024) {
    float4 v4 = *(const float4*)(row + i * 4);
    float vv[4] = { v4.x, v4.y, v4.z, v4.w };
    #pragma unroll
    for (int j = 0; j < 4; ++j) {
      const int c = i * 4 + j;
      const float v = vv[j];
      const bool isl = (c == lb);
      const float tmp = isl ? (tg - 2.0f) : v;
      if (tmp > tg) cnt++;
      sexp += exp2f(v * EXP2K);
      u64 pk = ((u64)ordkey(v) << 32) | (u32)(0xFFFFFFFFu - (u32)c);
      if (pk > best) best = pk;
      if (!isl && v <= tg && v >= THRC) {
        u32 p = atomicAdd(&scal[1], 1u);
        if (p < CAP) buf[p] = ((u64)ordkey(v) << 32) | (u32)r;
      }
    }
  }
  sc[tid] = cnt; se[tid] = sexp; sm[tid] = best;
  __syncthreads();
  for (int st = 512; st > 0; st >>= 1) {
    if (tid < st) {
      sc[tid] += sc[tid + st];
      se[tid] += se[tid + st];
      if (sm[tid + st] > sm[tid]) sm[tid] = sm[tid + st];
    }
    __syncthreads();
  }
  if (tid == 0) {
    atomicAdd(&scal[0], sc[0]);
    sexpws[r] = se[0];
    amaxws[r] = 0xFFFFFFFFu - (u32)(sm[0] & 0xFFFFFFFFu);
  }
}

// ---------------- K3: finisher (1 block): select th + stats + loss ----
__global__ __launch_bounds__(1024) void k_finish(const u64* __restrict__ buf,
                                                 const u32* __restrict__ scal,
                                                 const int* __restrict__ lab,
                                                 const float* __restrict__ tgtws,
                                                 const float* __restrict__ sexpws,
                                                 const u32* __restrict__ amaxws,
                                                 float* __restrict__ out) {
  __shared__ u32 hist[4096];
  __shared__ u32 s[1024], cs[1024];
  __shared__ u32 sb1, sr1, sb2, sr2, sthkey, lcnt;
  __shared__ u64 lbuf[512];
  __shared__ float rl[256], ra[256];
  const int tid = threadIdx.x;
  const int n = (int)min(scal[1], (u32)CAP);
  const int topk = (int)scal[0];
  int a = 25599744 - topk; if (a < 0) a = 0;               // B*(C-1)=25599744
  int k = (int)ceilf((1.0f / 99999.0f) * (float)a);        // mirror ref f32 math
  if (k < 1) k = 1;

  if (tid == 0) { sb1 = 0; sr1 = 1; sb2 = 0; sr2 = 1; lcnt = 0; }
  // ---- level 1: key bits 31..20 ----
  for (int i = tid; i < 4096; i += 1024) hist[i] = 0;
  __syncthreads();
  for (int i = tid; i < n; i += 1024) atomicAdd(&hist[(u32)(buf[i] >> 52)], 1u);
  __syncthreads();
  {
    u32 h[4]; u32 c = 0;
    #pragma unroll
    for (int j = 0; j < 4; ++j) { h[j] = hist[tid * 4 + j]; c += h[j]; }
    cs[tid] = c; s[tid] = c;
    __syncthreads();
    for (int off = 1; off < 1024; off <<= 1) {
      u32 v = (tid + off < 1024) ? s[tid + off] : 0u;
      __syncthreads(); s[tid] += v; __syncthreads();
    }
    u32 incl = s[tid], excl = incl - cs[tid];
    if ((int)excl < k && (int)incl >= k) {
      u32 cum = excl;
      for (int j = 3; j >= 0; --j) {
        cum += h[j];
        if ((int)cum >= k) { sb1 = tid * 4 + j; sr1 = (u32)k - (cum - h[j]); break; }
      }
    }
  }
  __syncthreads();
  const u32 b1 = sb1, r1 = sr1;
  // ---- level 2: key bits 19..8 ----
  for (int i = tid; i < 4096; i += 1024) hist[i] = 0;
  __syncthreads();
  for (int i = tid; i < n; i += 1024) {
    u32 key = (u32)(buf[i] >> 32);
    if ((key >> 20) == b1) atomicAdd(&hist[(key >> 8) & 4095u], 1u);
  }
  __syncthreads();
  {
    u32 h[4]; u32 c = 0;
    #pragma unroll
    for (int j = 0; j < 4; ++j) { h[j] = hist[tid * 4 + j]; c += h[j]; }
    cs[tid] = c; s[tid] = c;
    __syncthreads();
    for (int off = 1; off < 1024; off <<= 1) {
      u32 v = (tid + off < 1024) ? s[tid + off] : 0u;
      __syncthreads(); s[tid] += v; __syncthreads();
    }
    u32 incl = s[tid], excl = incl - cs[tid];
    if (excl < r1 && incl >= r1) {
      u32 cum = excl;
      for (int j = 3; j >= 0; --j) {
        cum += h[j];
        if (cum >= r1) { sb2 = tid * 4 + j; sr2 = r1 - (cum - h[j]); break; }
      }
    }
  }
  __syncthreads();
  const u32 b2 = sb2, r2 = sr2;
  // ---- level 3: key bits 7..0 ----
  for (int i = tid; i < 256; i += 1024) hist[i] = 0;
  __syncthreads();
  const u32 pfx = (b1 << 12) | b2;
  for (int i = tid; i < n; i += 1024) {
    u32 key = (u32)(buf[i] >> 32);
    if ((key >> 8) == pfx) atomicAdd(&hist[key & 255u], 1u);
  }
  __syncthreads();
  if (tid == 0) {
    u32 cum = 0, b3 = 0;
    for (int j = 255; j >= 0; --j) { cum += hist[j]; if (cum >= r2) { b3 = (u32)j; break; } }
    sthkey = (b1 << 20) | (b2 << 8) | b3;
  }
  __syncthreads();
  const u32 thk = sthkey;
  // ---- collect strictly-greater entries (<= k-1 <= 256 of them) ----
  for (int i = tid; i < n; i += 1024) {
    u64 e = buf[i];
    if ((u32)(e >> 32) > thk) { u32 p = atomicAdd(&lcnt, 1u); if (p < 512) lbuf[p] = e; }
  }
  __syncthreads();
  const int m = (int)min(lcnt, 512u);
  if (tid < 256) {
    const int r = tid;
    int cnt = 0; float ssq = 0.f;
    for (int j = 0; j < m; ++j) {
      u64 e = lbuf[j];
      if ((u32)(e & 0xFFFFFFFFu) == (u32)r) {
        float v = inv_ordkey((u32)(e >> 32));
        cnt++; ssq += v * v;
      }
    }
    const float tg = tgtws[r];
    const float times = fmaxf((float)cnt, 1.0f);
    const float nm = ssq / times;
    const float tgm = (tg - 0.4f) - (1.0f + tg) * nm;
    const float sexp = sexpws[r] - exp2f(EXP2K * tg) + exp2f(EXP2K * tgm);
    rl[r] = logf(sexp) - 64.0f * tgm;
    ra[r] = (amaxws[r] == (u32)lab[r]) ? 1.0f : 0.0f;
  }
  __syncthreads();
  for (int st = 128; st > 0; st >>= 1) {
    if (tid < st) { rl[tid] += rl[tid + st]; ra[tid] += ra[tid + st]; }
    __syncthreads();
  }
  if (tid == 0) { out[0] = rl[0] * (1.0f / 256.0f); out[1] = ra[0] * (1.0f / 256.0f); }
}

extern "C" void kernel_launch(void* const* d_in, const int* in_sizes, int n_in,
                              void* d_out, int out_size, void* d_ws, size_t ws_size,
                              hipStream_t stream) {
  const float* emb = (const float*)d_in[0];
  const int* lab = (const int*)d_in[1];
  const float* kern = (const float*)d_in[2];
  float* out = (float*)d_out;
  char* ws = (char*)d_ws;

  u16* embn = (u16*)(ws + OFF_EMBN);
  float* tgtws = (float*)(ws + OFF_TGT);
  float* sexpws = (float*)(ws + OFF_SEXP);
  u32* amaxws = (u32*)(ws + OFF_AMAX);
  u32* scal = (u32*)(ws + OFF_SCAL);   // [0]=topk [1]=bufcnt
  float* cosb = (float*)(ws + OFF_COS);
  u64* buf = (u64*)(ws + OFF_BUF);

  hipMemsetAsync(scal, 0, 16, stream);
  k_prep<<<NB, 128, 0, stream>>>(emb, embn);
  k_gemm<<<(NC + 127) / 128, 512, 0, stream>>>(kern, embn, cosb);
  k_scan<<<NB, 1024, 0, stream>>>(cosb, lab, tgtws, sexpws, amaxws, scal, buf);
  k_finish<<<1, 1024, 0, stream>>>(buf, scal, lab, tgtws, sexpws, amaxws, out);
}